// Round 4
// baseline (465.044 us; speedup 1.0000x reference)
//
#include <hip/hip_runtime.h>

// Problem constants
#define BB   16
#define NQ   1024
#define NK   2048
#define DD   512
#define VV   512
#define OO   256
#define SCALE 0.044194173824159216f  // 1/sqrt(512)

typedef __attribute__((ext_vector_type(4))) float f32x4;
typedef __attribute__((ext_vector_type(8))) short s16x8;

#define AS1(p) ((const __attribute__((address_space(1))) void*)(p))
#define AS3(p) ((__attribute__((address_space(3))) void*)(p))

__device__ __forceinline__ unsigned short f2bf(float f) {
  unsigned u = __float_as_uint(f);
  u += 0x7fffu + ((u >> 16) & 1u);   // round-to-nearest-even (finite inputs)
  return (unsigned short)(u >> 16);
}
__device__ __forceinline__ float bf2f(unsigned short b) {
  return __uint_as_float(((unsigned)b) << 16);
}

// ---------------------------------------------------------------------------
// Core: C(128x128) = A(128xK) * B(128xK)^T in bf16 MFMA, m97 structure.
// ---------------------------------------------------------------------------
__device__ __forceinline__ void gemm_bt_core(
    const unsigned short* __restrict__ Abase,
    const unsigned short* __restrict__ Bbase,
    int K,
    unsigned short* As, unsigned short* Bs,   // [128*32] each (8 KB each)
    f32x4 acc[4][4])
{
  const int t = threadIdx.x;
  const int w = t >> 6;
  const int l = t & 63;
  const int srow = l >> 2;
  const int scol = (l & 3) * 8;
  const int r0 = (w * 2 + 0) * 16 + srow;
  const int r1 = (w * 2 + 1) * 16 + srow;
  const int lds0 = (w * 2 + 0) * 512 + l * 8;
  const int lds1 = (w * 2 + 1) * 512 + l * 8;
  const int wm = (w >> 1) * 64;
  const int wn = (w & 1) * 64;
  const int lm = l & 15;
  const int lq = l >> 4;

  for (int kt = 0; kt < K; kt += 32) {
    __builtin_amdgcn_global_load_lds(AS1(Abase + (size_t)r0 * K + kt + scol), AS3(As + lds0), 16, 0, 0);
    __builtin_amdgcn_global_load_lds(AS1(Abase + (size_t)r1 * K + kt + scol), AS3(As + lds1), 16, 0, 0);
    __builtin_amdgcn_global_load_lds(AS1(Bbase + (size_t)r0 * K + kt + scol), AS3(Bs + lds0), 16, 0, 0);
    __builtin_amdgcn_global_load_lds(AS1(Bbase + (size_t)r1 * K + kt + scol), AS3(Bs + lds1), 16, 0, 0);
    __syncthreads();
    s16x8 af[4], bfr[4];
    #pragma unroll
    for (int i = 0; i < 4; ++i) {
      af[i]  = *(const s16x8*)(As + (wm + i * 16 + lm) * 32 + lq * 8);
      bfr[i] = *(const s16x8*)(Bs + (wn + i * 16 + lm) * 32 + lq * 8);
    }
    #pragma unroll
    for (int mi = 0; mi < 4; ++mi)
      #pragma unroll
      for (int ni = 0; ni < 4; ++ni)
        acc[mi][ni] = __builtin_amdgcn_mfma_f32_16x16x32_bf16(af[mi], bfr[ni], acc[mi][ni], 0, 0, 0);
    __syncthreads();
  }
}

// C/D layout (m89/m91): col = lane&15, row = (lane>>4)*4 + reg

#define CS_STRIDE 136   // shorts; 272 B/row: 16B-aligned rows, conflict-padded

// ---------------------------------------------------------------------------
// GEMM1 fused: P'[b,q,k] = mask ? exp(scale * Q.K^T) : 0   (bf16, unnormalized)
//              sums[b,q] += row-partials (atomic)
// Mask is prefetched BEFORE the K-loop and compressed to 64 bits/thread so the
// 134 MB mask stream overlaps the GEMM phase (across resident blocks).
// No max-subtraction needed: |logit| <= ~6 (sigma=1), exp stays in fp32 range.
// ---------------------------------------------------------------------------
__global__ __launch_bounds__(256)
void qk_kernel(const unsigned short* __restrict__ Qb,
               const unsigned short* __restrict__ Kb,
               const int* __restrict__ mask,
               unsigned short* __restrict__ S,
               float* __restrict__ sums)
{
  const int b  = blockIdx.z;
  const int tm = blockIdx.y;   // 8
  const int tn = blockIdx.x;   // 16
  __shared__ unsigned short smem[128 * CS_STRIDE];   // 34.8 KB
  unsigned short* As = smem;
  unsigned short* Bs = smem + 4096;
  unsigned short* Cs = smem;
  const int t = threadIdx.x, w = t >> 6, l = t & 63;
  const int trow = t >> 4, tcol = (t & 15) * 8;

  // --- mask prefetch & compress: 8 rows x 8 cols per thread -> 2 VGPRs ---
  unsigned mbits0 = 0, mbits1 = 0;
  #pragma unroll
  for (int it = 0; it < 8; ++it) {
    const int row = it * 16 + trow;
    const size_t gbase = ((size_t)b * NQ + tm * 128 + row) * NK + tn * 128 + tcol;
    const int4 m0 = *(const int4*)(mask + gbase);
    const int4 m1 = *(const int4*)(mask + gbase + 4);
    unsigned byte = (m0.x ? 1u : 0u) | (m0.y ? 2u : 0u) | (m0.z ? 4u : 0u) | (m0.w ? 8u : 0u)
                  | (m1.x ? 16u : 0u) | (m1.y ? 32u : 0u) | (m1.z ? 64u : 0u) | (m1.w ? 128u : 0u);
    if (it < 4) mbits0 |= byte << (8 * it);
    else        mbits1 |= byte << (8 * (it - 4));
  }

  f32x4 acc[4][4];
  #pragma unroll
  for (int i = 0; i < 4; ++i)
    #pragma unroll
    for (int j = 0; j < 4; ++j) acc[i][j] = (f32x4){0.f, 0.f, 0.f, 0.f};

  gemm_bt_core(Qb + ((size_t)b * NQ + tm * 128) * DD,
               Kb + ((size_t)b * NK + tn * 128) * DD, DD, As, Bs, acc);

  const int wm = (w >> 1) * 64, wn = (w & 1) * 64;
  const int lm = l & 15, lq = l >> 4;
  #pragma unroll
  for (int mi = 0; mi < 4; ++mi)
    #pragma unroll
    for (int ni = 0; ni < 4; ++ni)
      #pragma unroll
      for (int r = 0; r < 4; ++r)
        Cs[(wm + mi * 16 + lq * 4 + r) * CS_STRIDE + wn + ni * 16 + lm] =
            f2bf(acc[mi][ni][r] * SCALE);
  __syncthreads();

  #pragma unroll
  for (int it = 0; it < 8; ++it) {
    const int row = it * 16 + trow;
    const int gq = tm * 128 + row;
    const size_t gbase = ((size_t)b * NQ + gq) * NK + tn * 128 + tcol;
    s16x8 v = *(const s16x8*)(Cs + row * CS_STRIDE + tcol);
    const unsigned byte = ((it < 4) ? (mbits0 >> (8 * it)) : (mbits1 >> (8 * (it - 4)))) & 0xffu;
    float e[8];
    #pragma unroll
    for (int j = 0; j < 8; ++j)
      e[j] = (byte >> j & 1u) ? __expf(bf2f((unsigned short)v[j])) : 0.f;
    float sp = 0.f;
    #pragma unroll
    for (int j = 0; j < 8; ++j) sp += e[j];
    #pragma unroll
    for (int off = 8; off > 0; off >>= 1) sp += __shfl_down(sp, off, 16);
    if ((t & 15) == 0) atomicAdd(&sums[(size_t)b * NQ + gq], sp);
    s16x8 o;
    #pragma unroll
    for (int j = 0; j < 8; ++j) o[j] = (short)f2bf(e[j]);
    *(s16x8*)(S + gbase) = o;
  }
}

// ---------------------------------------------------------------------------
// GEMM2: Ctx[b,q,v] = (P' . Vt^T) / sums[b,q]   (bf16 out)
// ---------------------------------------------------------------------------
__global__ __launch_bounds__(256)
void pv_kernel(const unsigned short* __restrict__ P,
               const unsigned short* __restrict__ Vt,
               const float* __restrict__ sums,
               unsigned short* __restrict__ Ctx)
{
  const int b  = blockIdx.z;
  const int tm = blockIdx.y;   // 8
  const int tn = blockIdx.x;   // 4
  __shared__ unsigned short smem[128 * CS_STRIDE];
  __shared__ float Ls[128];
  unsigned short* As = smem;
  unsigned short* Bs = smem + 4096;
  unsigned short* Cs = smem;
  const int t = threadIdx.x;
  if (t < 128) Ls[t] = 1.0f / sums[(size_t)b * NQ + tm * 128 + t];
  f32x4 acc[4][4];
  #pragma unroll
  for (int i = 0; i < 4; ++i)
    #pragma unroll
    for (int j = 0; j < 4; ++j) acc[i][j] = (f32x4){0.f, 0.f, 0.f, 0.f};

  gemm_bt_core(P  + ((size_t)b * NQ + tm * 128) * NK,
               Vt + ((size_t)b * VV + tn * 128) * NK, NK, As, Bs, acc);
  // core's internal __syncthreads() orders Ls writes before epilogue reads

  const int w = t >> 6, l = t & 63;
  const int wm = (w >> 1) * 64, wn = (w & 1) * 64;
  const int lm = l & 15, lq = l >> 4;
  #pragma unroll
  for (int mi = 0; mi < 4; ++mi)
    #pragma unroll
    for (int ni = 0; ni < 4; ++ni)
      #pragma unroll
      for (int r = 0; r < 4; ++r) {
        const int row = wm + mi * 16 + lq * 4 + r;
        Cs[row * CS_STRIDE + wn + ni * 16 + lm] = f2bf(acc[mi][ni][r] * Ls[row]);
      }
  __syncthreads();
  const int trow = t >> 4, tcol = (t & 15) * 8;
  #pragma unroll
  for (int it = 0; it < 8; ++it) {
    const int row = it * 16 + trow;
    s16x8 v = *(const s16x8*)(Cs + row * CS_STRIDE + tcol);
    *(s16x8*)(Ctx + ((size_t)b * NQ + tm * 128 + row) * VV + tn * 128 + tcol) = v;
  }
}

// ---------------------------------------------------------------------------
// GEMM3: out = Ctx . W^T + bias  (fp32 out, vectorized epilogue)
// ---------------------------------------------------------------------------
#define CSF_STRIDE 136  // floats
__global__ __launch_bounds__(256)
void rs_kernel(const unsigned short* __restrict__ Ctx,
               const unsigned short* __restrict__ Wb,
               const float* __restrict__ bias,
               float* __restrict__ out)
{
  const int tm = blockIdx.y;   // 128
  const int tn = blockIdx.x;   // 2
  __shared__ float smemf[128 * CSF_STRIDE];   // 69.6 KB
  unsigned short* As = (unsigned short*)smemf;
  unsigned short* Bs = (unsigned short*)smemf + 4096;
  float* Cs = smemf;
  f32x4 acc[4][4];
  #pragma unroll
  for (int i = 0; i < 4; ++i)
    #pragma unroll
    for (int j = 0; j < 4; ++j) acc[i][j] = (f32x4){0.f, 0.f, 0.f, 0.f};

  gemm_bt_core(Ctx + (size_t)tm * 128 * VV,
               Wb + (size_t)tn * 128 * VV, VV, As, Bs, acc);

  const int t = threadIdx.x, w = t >> 6, l = t & 63;
  const int wm = (w >> 1) * 64, wn = (w & 1) * 64;
  const int lm = l & 15, lq = l >> 4;
  #pragma unroll
  for (int mi = 0; mi < 4; ++mi)
    #pragma unroll
    for (int ni = 0; ni < 4; ++ni)
      #pragma unroll
      for (int r = 0; r < 4; ++r)
        Cs[(wm + mi * 16 + lq * 4 + r) * CSF_STRIDE + wn + ni * 16 + lm] = acc[mi][ni][r];
  __syncthreads();
  const int trow = t >> 4, tcol = (t & 15) * 8;
  #pragma unroll
  for (int it = 0; it < 8; ++it) {
    const int row = it * 16 + trow;
    f32x4 a = *(const f32x4*)(Cs + row * CSF_STRIDE + tcol);
    f32x4 c = *(const f32x4*)(Cs + row * CSF_STRIDE + tcol + 4);
    const int gn = tn * 128 + tcol;
    const f32x4 b0 = *(const f32x4*)(bias + gn);
    const f32x4 b1 = *(const f32x4*)(bias + gn + 4);
    a += b0; c += b1;
    float* o = out + (size_t)(tm * 128 + row) * OO + gn;
    *(f32x4*)o = a;
    *(f32x4*)(o + 4) = c;
  }
}

// ---------------------------------------------------------------------------
// prep: all fp32->bf16 converts + V transpose + sums zeroing in ONE launch.
// Branches are block-uniform (no divergence).
// blocks: [0,4096) cvt Q | [4096,12288) cvt K | [12288,12352) cvt W
//         [12352,16448) vt | [16448,16512) zero sums
// ---------------------------------------------------------------------------
#define VT_STRIDE 68  // floats
__device__ __forceinline__ void cvt8(const float* __restrict__ in,
                                     unsigned short* __restrict__ out, int i)
{
  const float4* p = (const float4*)in + (size_t)i * 2;
  const float4 a = p[0], b = p[1];
  s16x8 o;
  o[0] = (short)f2bf(a.x); o[1] = (short)f2bf(a.y);
  o[2] = (short)f2bf(a.z); o[3] = (short)f2bf(a.w);
  o[4] = (short)f2bf(b.x); o[5] = (short)f2bf(b.y);
  o[6] = (short)f2bf(b.z); o[7] = (short)f2bf(b.w);
  ((s16x8*)out)[i] = o;
}

__global__ __launch_bounds__(256)
void prep_kernel(const float* __restrict__ q, const float* __restrict__ k,
                 const float* __restrict__ w, const float* __restrict__ v,
                 unsigned short* __restrict__ Qb, unsigned short* __restrict__ Kb,
                 unsigned short* __restrict__ Wb, unsigned short* __restrict__ Vt,
                 float* __restrict__ sums)
{
  __shared__ float tile[64 * VT_STRIDE];
  const int bid = blockIdx.x;
  const int t = threadIdx.x;
  if (bid < 4096) {
    cvt8(q, Qb, bid * 256 + t);
  } else if (bid < 12288) {
    cvt8(k, Kb, (bid - 4096) * 256 + t);
  } else if (bid < 12352) {
    cvt8(w, Wb, (bid - 12288) * 256 + t);
  } else if (bid < 16448) {
    const int flat = bid - 12352;
    const int b  = flat >> 8;
    const int rem = flat & 255;
    const int k0 = (rem >> 3) * 64;
    const int v0 = (rem & 7) * 64;
    const int lr = t >> 4, lc4 = (t & 15) * 4;
    #pragma unroll
    for (int j = 0; j < 4; ++j) {
      const int row = lr + j * 16;  // k
      const float4 x = *(const float4*)(v + ((size_t)b * NK + k0 + row) * VV + v0 + lc4);
      *(float4*)(tile + row * VT_STRIDE + lc4) = x;
    }
    __syncthreads();
    const int vr = t >> 3, kx = (t & 7) * 8;
    #pragma unroll
    for (int j = 0; j < 2; ++j) {
      const int vv = vr + j * 32;
      s16x8 o;
      #pragma unroll
      for (int i = 0; i < 8; ++i) o[i] = (short)f2bf(tile[(kx + i) * VT_STRIDE + vv]);
      *(s16x8*)(Vt + ((size_t)b * VV + v0 + vv) * NK + k0 + kx) = o;
    }
  } else {
    const int i = (bid - 16448) * 256 + t;
    if (i < BB * NQ) sums[i] = 0.f;
  }
}

// ---------------------------------------------------------------------------
extern "C" void kernel_launch(void* const* d_in, const int* in_sizes, int n_in,
                              void* d_out, int out_size, void* d_ws, size_t ws_size,
                              hipStream_t stream)
{
  const float* keys    = (const float*)d_in[0];  // [B, NK, D]
  const float* queries = (const float*)d_in[1];  // [B, NQ, D]
  const float* values  = (const float*)d_in[2];  // [B, NK, V]
  const int*   mask    = (const int*)  d_in[3];  // [B, NQ, NK]
  const float* W       = (const float*)d_in[4];  // [O, V]
  const float* bias    = (const float*)d_in[5];  // [O]
  float* out = (float*)d_out;                    // [B, NQ, O]

  char* ws = (char*)d_ws;
  // layout (MiB): Qb 16 | Kb 32 | Vt 32 | Wb 1 | S 64 | sums 64KB => ~145 MiB
  unsigned short* Qb = (unsigned short*)(ws);
  unsigned short* Kb = (unsigned short*)(ws + (16ull << 20));
  unsigned short* Vt = (unsigned short*)(ws + (48ull << 20));
  unsigned short* Wb = (unsigned short*)(ws + (80ull << 20));
  unsigned short* S  = (unsigned short*)(ws + (81ull << 20));
  float* sums        = (float*)(ws + (145ull << 20));
  unsigned short* Ctx = Qb;  // Qb dead after qk_kernel; stream order serializes

  prep_kernel<<<dim3(16512), 256, 0, stream>>>(queries, keys, W, values,
                                               Qb, Kb, Wb, Vt, sums);
  qk_kernel<<<dim3(NK / 128, NQ / 128, BB), 256, 0, stream>>>(Qb, Kb, mask, S, sums);
  pv_kernel<<<dim3(VV / 128, NQ / 128, BB), 256, 0, stream>>>(S, Vt, sums, Ctx);
  rs_kernel<<<dim3(OO / 128, (BB * NQ) / 128, 1), 256, 0, stream>>>(Ctx, Wb, bias, out);
}